// Round 4
// baseline (303.131 us; speedup 1.0000x reference)
//
#include <hip/hip_runtime.h>

typedef _Float16 f16;
typedef _Float16 f16x8 __attribute__((ext_vector_type(8)));
typedef _Float16 f16x4 __attribute__((ext_vector_type(4)));
typedef float    f32x4 __attribute__((ext_vector_type(4)));

static constexpr int BATCH = 2, SEQ = 2048, DMODEL = 1024, HEADS = 16, DHEAD = 64;
static constexpr int MTOK = BATCH * SEQ;  // 4096 tokens
static constexpr float LOG2E = 1.44269504088896f;

// async global->LDS, 16B per lane, LDS dest = wave-uniform base + lane*16
#define GLOBAL_LOAD_LDS16(gptr, lptr)                                              \
  __builtin_amdgcn_global_load_lds(                                                \
      (const __attribute__((address_space(1))) void*)(gptr),                       \
      (__attribute__((address_space(3))) void*)(lptr), 16, 0, 0)

#define MFMA16(a, b, c) __builtin_amdgcn_mfma_f32_16x16x32_f16((a), (b), (c), 0, 0, 0)

__device__ __forceinline__ float fexp2(float x) {
  float r;
  asm volatile("v_exp_f32 %0, %1" : "=v"(r) : "v"(x));
  return r;
}

// ---- 64x32 f16 image block (4KB = 2048 f16), paired-row XOR swizzle ----
// logical (mr in [0,64), kr in [0,32)) -> f16 offset within block.
__device__ __forceinline__ int imgAB(int mr, int kr) {
  int pr = mr >> 1;
  int jj = ((mr & 1) << 2) | (kr >> 3);
  int j = jj ^ (pr & 7);
  return pr * 64 + j * 8 + (kr & 7);
}

// ---------------- cast fp32 -> f16 image layout ----------------
__global__ __launch_bounds__(256) void cast_kernel(const float* __restrict__ src,
                                                   f16* __restrict__ dst) {
  int c = blockIdx.x * 256 + threadIdx.x;  // chunk id
  int blk = c >> 8, cb = c & 255;
  int pr = cb >> 3, j = cb & 7;
  int jj = j ^ (pr & 7);
  int mr = (pr << 1) | (jj >> 2);
  int kr = (jj & 3) << 3;
  int m = (blk >> 5) * 64 + mr;
  int k = (blk & 31) * 32 + kr;
  const float* s = src + (size_t)m * DMODEL + k;
  f32x4 a = *(const f32x4*)s, b = *(const f32x4*)(s + 4);
  f16x8 o;
  o[0] = (f16)a[0]; o[1] = (f16)a[1]; o[2] = (f16)a[2]; o[3] = (f16)a[3];
  o[4] = (f16)b[0]; o[5] = (f16)b[1]; o[6] = (f16)b[2]; o[7] = (f16)b[3];
  *(f16x8*)(dst + (size_t)c * 8) = o;
}

// ------------- weight transpose+cast to image: B[n][k] = w[k][n] -------------
__global__ __launch_bounds__(256) void transw_kernel(
    const float* __restrict__ w0, const float* __restrict__ w1,
    const float* __restrict__ w2, const float* __restrict__ w3,
    f16* __restrict__ Wimg) {
  const int z = blockIdx.z;
  const float* w = z == 0 ? w0 : z == 1 ? w1 : z == 2 ? w2 : w3;
  f16* t = Wimg + (size_t)z * DMODEL * DMODEL;
  __shared__ f16 lt[64][72];
  const int k0 = blockIdx.x * 64, n0 = blockIdx.y * 64;
  const int r = threadIdx.x >> 2, c0 = (threadIdx.x & 3) * 16;
  const float* src = w + (size_t)(k0 + r) * DMODEL + n0 + c0;
#pragma unroll
  for (int jx = 0; jx < 16; jx += 4) {
    f32x4 x = *(const f32x4*)(src + jx);
    lt[c0 + jx + 0][r] = (f16)x[0];
    lt[c0 + jx + 1][r] = (f16)x[1];
    lt[c0 + jx + 2][r] = (f16)x[2];
    lt[c0 + jx + 3][r] = (f16)x[3];
  }
  __syncthreads();
  const int n = n0 + r;
#pragma unroll
  for (int cw = 0; cw < 2; cw++) {
    int k = k0 + c0 + cw * 8;
    int blk = ((n >> 6) << 5) | (k >> 5);
    int off = blk * 2048 + imgAB(n & 63, k & 31);
    f16x8 v;
#pragma unroll
    for (int e = 0; e < 8; e++) v[e] = lt[r][c0 + cw * 8 + e];
    *(f16x8*)(t + off) = v;
  }
}

// ------- fused QKV projection GEMM: 128x128 tile, BK=64, 4 waves, z-fused ------
// z=0: Qp linear f16 scaled by log2(e).  z=1: Kp linear f16.
// z=2: Vt[b,h,dh,s] scatter (contiguous f16x4 along s).
__global__ __launch_bounds__(256) void proj_kernel(
    const f16* __restrict__ Ximg, const f16* __restrict__ Wimg,
    const float* __restrict__ bq, const float* __restrict__ bk,
    const float* __restrict__ bv, f16* __restrict__ Qp, f16* __restrict__ Kp,
    f16* __restrict__ Vt, int zbase, size_t aStride) {
  __shared__ f16 As[8192];  // 4 image blocks: 128 m-rows x 64 k
  __shared__ f16 Bs[8192];
  const int z = zbase + blockIdx.z;
  const f16* A = Ximg + (size_t)blockIdx.z * aStride;
  const f16* Bw = Wimg + (size_t)z * DMODEL * DMODEL;
  int lin = blockIdx.x + (blockIdx.y << 3);
  int swz = ((lin & 7) << 5) + (lin >> 3);
  const int n0 = (swz & 7) * 128, m0 = (swz >> 3) * 128;
  const int tid = threadIdx.x, w = tid >> 6, l = tid & 63, q = l & 15, g = l >> 4;
  const int wr = w >> 1, wc = w & 1;
  int aoff[4][2], boff[4][2];
#pragma unroll
  for (int mi = 0; mi < 4; mi++) {
    int mr = wr * 64 + mi * 16 + q;
#pragma unroll
    for (int kb = 0; kb < 2; kb++)
      aoff[mi][kb] = (((mr >> 6) << 1) | kb) * 2048 + imgAB(mr & 63, g * 8);
  }
#pragma unroll
  for (int ni = 0; ni < 4; ni++) {
    int nr = wc * 64 + ni * 16 + q;
#pragma unroll
    for (int kb = 0; kb < 2; kb++)
      boff[ni][kb] = (((nr >> 6) << 1) | kb) * 2048 + imgAB(nr & 63, g * 8);
  }
  f32x4 acc[4][4] = {};
  for (int t = 0; t < 16; t++) {
#pragma unroll
    for (int i = 0; i < 4; i++) {
      int c = w * 4 + i;            // 16 chunks of 1KB each for A and B
      int bi = c >> 2, part = c & 3;
      size_t gblk = (size_t)(((m0 >> 6) + (bi >> 1)) * 32 + t * 2 + (bi & 1));
      GLOBAL_LOAD_LDS16(A + gblk * 2048 + part * 512 + l * 8, (char*)&As[c * 512]);
      size_t gblk2 = (size_t)(((n0 >> 6) + (bi >> 1)) * 32 + t * 2 + (bi & 1));
      GLOBAL_LOAD_LDS16(Bw + gblk2 * 2048 + part * 512 + l * 8, (char*)&Bs[c * 512]);
    }
    __syncthreads();
    f16x8 af[4][2], bf[4][2];
#pragma unroll
    for (int mi = 0; mi < 4; mi++) {
      af[mi][0] = *(const f16x8*)&As[aoff[mi][0]];
      af[mi][1] = *(const f16x8*)&As[aoff[mi][1]];
    }
#pragma unroll
    for (int ni = 0; ni < 4; ni++) {
      bf[ni][0] = *(const f16x8*)&Bs[boff[ni][0]];
      bf[ni][1] = *(const f16x8*)&Bs[boff[ni][1]];
    }
#pragma unroll
    for (int mi = 0; mi < 4; mi++)
#pragma unroll
      for (int ni = 0; ni < 4; ni++) {
        acc[mi][ni] = MFMA16(af[mi][0], bf[ni][0], acc[mi][ni]);
        acc[mi][ni] = MFMA16(af[mi][1], bf[ni][1], acc[mi][ni]);
      }
    __syncthreads();
  }
  const float* bias = z == 0 ? bq : (z == 1 ? bk : bv);
#pragma unroll
  for (int mi = 0; mi < 4; mi++)
#pragma unroll
    for (int ni = 0; ni < 4; ni++) {
      const int col = n0 + wc * 64 + ni * 16 + q;
      const float bvl = bias[col];
      const int row0 = m0 + wr * 64 + mi * 16 + g * 4;
      if (z == 0) {
#pragma unroll
        for (int r = 0; r < 4; r++)
          Qp[(size_t)(row0 + r) * DMODEL + col] = (f16)((acc[mi][ni][r] + bvl) * LOG2E);
      } else if (z == 1) {
#pragma unroll
        for (int r = 0; r < 4; r++)
          Kp[(size_t)(row0 + r) * DMODEL + col] = (f16)(acc[mi][ni][r] + bvl);
      } else {
        const int h = col >> 6, dh = col & 63;
        const int b2 = row0 >> 11, s0 = row0 & (SEQ - 1);
        f16* dst = Vt + ((size_t)(b2 * HEADS + h) * DHEAD + dh) * SEQ + s0;
        f16x4 ov;
        ov[0] = (f16)(acc[mi][ni][0] + bvl); ov[1] = (f16)(acc[mi][ni][1] + bvl);
        ov[2] = (f16)(acc[mi][ni][2] + bvl); ov[3] = (f16)(acc[mi][ni][3] + bvl);
        *(f16x4*)dst = ov;
      }
    }
}

// ---------------- flash attention, barrier-free reg-streaming ----------------
// 1 wave per block, 32 q-rows per wave (frags A,B), KV tile = 32, 2-stage
// register pipeline for K/V loads (no LDS staging, no __syncthreads).
// Scores pre-scaled by log2e (folded into Qp). Defer-max online softmax.
// Output written in out-GEMM image layout with the reference's transpose-bug
// scramble: b'=h>>3, s'=((2h+b)&15)*128+s/16, d'=(s%16)*64+dh.
__global__ __launch_bounds__(64, 2) void attn_kernel(
    const f16* __restrict__ Qp, const f16* __restrict__ Kp,
    const f16* __restrict__ Vt, f16* __restrict__ Simg) {
  __shared__ f16 Plds[1024];  // two wave-private P tiles (frag A, frag B)
  const int l = threadIdx.x, q = l & 15, g = l >> 4;
  const int bid = blockIdx.x;
  const int gid = (bid & 7) * 256 + (bid >> 3);  // chunked XCD swizzle
  const int bh = gid >> 6, qt = gid & 63;
  const int b = bh >> 4, h = bh & 15;
  const int q0 = qt * 32;

  const f16* qra = Qp + (size_t)(b * SEQ + q0 + q) * DMODEL + h * 64;
  const f16x8 qa0 = *(const f16x8*)(qra + g * 8);
  const f16x8 qa1 = *(const f16x8*)(qra + 32 + g * 8);
  const f16* qrb = qra + (size_t)16 * DMODEL;
  const f16x8 qb0 = *(const f16x8*)(qrb + g * 8);
  const f16x8 qb1 = *(const f16x8*)(qrb + 32 + g * 8);

  const f16* kp = Kp + ((size_t)b * SEQ + q) * DMODEL + h * 64 + g * 8;
  const f16* vp = Vt + ((size_t)bh * DHEAD + q) * SEQ + g * 8;

  float mA = -1.0e30f, mB = -1.0e30f, lA = 0.f, lB = 0.f;
  f32x4 oA[4] = {}, oB[4] = {};

  // P LDS offsets (wave-private image-swizzled 16x32 tile per frag)
  int pwoff[2];
  {
    const int pr = q >> 1;
#pragma unroll
    for (int fn = 0; fn < 2; fn++) {
      int jj = ((q & 1) << 2) | (fn * 2 + (g >> 1));
      pwoff[fn] = pr * 64 + ((jj ^ (pr & 7)) << 3) + (g & 1) * 4;
    }
  }
  const int poff = imgAB(q, g * 8);

  f16x8 Ak0, Ak1, Ak2, Ak3, Av0, Av1, Av2, Av3;
  f16x8 Bk0, Bk1, Bk2, Bk3, Bv0, Bv1, Bv2, Bv3;

#define LOADKV(S, t)                                                               \
  {                                                                                \
    const f16* kk_ = kp + (size_t)(t) * (32 * DMODEL);                             \
    S##k0 = *(const f16x8*)(kk_);                                                  \
    S##k1 = *(const f16x8*)(kk_ + 32);                                             \
    S##k2 = *(const f16x8*)(kk_ + 16 * DMODEL);                                    \
    S##k3 = *(const f16x8*)(kk_ + 16 * DMODEL + 32);                               \
    const f16* vv_ = vp + (t) * 32;                                                \
    S##v0 = *(const f16x8*)(vv_);                                                  \
    S##v1 = *(const f16x8*)(vv_ + 16 * SEQ);                                       \
    S##v2 = *(const f16x8*)(vv_ + 32 * SEQ);                                       \
    S##v3 = *(const f16x8*)(vv_ + 48 * SEQ);                                       \
  }

#define SOFTMAX_FRAG(s0, s1, m, lsum, o, pk0, pk1)                                 \
  {                                                                                \
    float lm = fmaxf(fmaxf(fmaxf(s0[0], s0[1]), fmaxf(s0[2], s0[3])),              \
                     fmaxf(fmaxf(s1[0], s1[1]), fmaxf(s1[2], s1[3])));             \
    if (!__all(lm <= m + 8.f)) {                                                   \
      float mx = fmaxf(lm, __shfl_xor(lm, 16, 64));                                \
      mx = fmaxf(mx, __shfl_xor(mx, 32, 64));                                      \
      const float mnew = fmaxf(m, mx);                                             \
      const float sc = fexp2(m - mnew);                                            \
      m = mnew;                                                                    \
      lsum *= sc;                                                                  \
      _Pragma("unroll")                                                            \
      for (int fo_ = 0; fo_ < 4; fo_++) {                                          \
        o[fo_][0] *= sc; o[fo_][1] *= sc; o[fo_][2] *= sc; o[fo_][3] *= sc;        \
      }                                                                            \
    }                                                                              \
    float ts = 0.f;                                                                \
    _Pragma("unroll")                                                              \
    for (int r_ = 0; r_ < 4; r_++) {                                               \
      float e0 = fexp2(s0[r_] - m);                                                \
      float e1 = fexp2(s1[r_] - m);                                                \
      ts += e0 + e1;                                                               \
      pk0[r_] = (f16)e0;                                                           \
      pk1[r_] = (f16)e1;                                                           \
    }                                                                              \
    lsum += ts;                                                                    \
  }

#define COMPUTE(S)                                                                 \
  {                                                                                \
    f32x4 sA0 = {}, sA1 = {}, sB0 = {}, sB1 = {};                                  \
    sA0 = MFMA16(S##k0, qa0, sA0); sA0 = MFMA16(S##k1, qa1, sA0);                  \
    sA1 = MFMA16(S##k2, qa0, sA1); sA1 = MFMA16(S##k3, qa1, sA1);                  \
    sB0 = MFMA16(S##k0, qb0, sB0); sB0 = MFMA16(S##k1, qb1, sB0);                  \
    sB1 = MFMA16(S##k2, qb0, sB1); sB1 = MFMA16(S##k3, qb1, sB1);                  \
    f16x4 pa0, pa1, pb0, pb1;                                                      \
    SOFTMAX_FRAG(sA0, sA1, mA, lA, oA, pa0, pa1);                                  \
    SOFTMAX_FRAG(sB0, sB1, mB, lB, oB, pb0, pb1);                                  \
    *(f16x4*)(&Plds[0] + pwoff[0]) = pa0;                                          \
    *(f16x4*)(&Plds[0] + pwoff[1]) = pa1;                                          \
    *(f16x4*)(&Plds[512] + pwoff[0]) = pb0;                                        \
    *(f16x4*)(&Plds[512] + pwoff[1]) = pb1;                                        \
    const f16x8 pfA = *(const f16x8*)(&Plds[0] + poff);                            \
    const f16x8 pfB = *(const f16x8*)(&Plds[512] + poff);                          \
    oA[0] = MFMA16(S##v0, pfA, oA[0]); oB[0] = MFMA16(S##v0, pfB, oB[0]);          \
    oA[1] = MFMA16(S##v1, pfA, oA[1]); oB[1] = MFMA16(S##v1, pfB, oB[1]);          \
    oA[2] = MFMA16(S##v2, pfA, oA[2]); oB[2] = MFMA16(S##v2, pfB, oB[2]);          \
    oA[3] = MFMA16(S##v3, pfA, oA[3]); oB[3] = MFMA16(S##v3, pfB, oB[3]);          \
  }

  LOADKV(A, 0);
  LOADKV(B, 1);
  for (int t = 0; t < 64; t += 2) {
    COMPUTE(A);
    if (t + 2 < 64) LOADKV(A, t + 2);
    COMPUTE(B);
    if (t + 3 < 64) LOADKV(B, t + 3);
  }

  // finalize: reduce l over the 4 g-groups, then scrambled store
  float lsA = lA + __shfl_xor(lA, 16, 64);
  lsA += __shfl_xor(lsA, 32, 64);
  float lsB = lB + __shfl_xor(lB, 16, 64);
  lsB += __shfl_xor(lsB, 32, 64);
  const float invA = 1.f / lsA, invB = 1.f / lsB;
  const int m16 = (2 * h + b) & 15, bp = h >> 3;
#pragma unroll
  for (int half = 0; half < 2; half++) {
    const int s = q0 + half * 16 + q;
    const int tp = bp * SEQ + m16 * 128 + (s >> 4);
    const float inv = half ? invB : invA;
    const f32x4* o = half ? oB : oA;
#pragma unroll
    for (int fo = 0; fo < 4; fo++) {
      const int d0 = (s & 15) * 64 + fo * 16 + g * 4;
      f16* dst = Simg + (size_t)(((tp >> 6) << 5) | (d0 >> 5)) * 2048 + imgAB(tp & 63, d0 & 31);
      f16x4 ov;
      ov[0] = (f16)(o[fo][0] * inv); ov[1] = (f16)(o[fo][1] * inv);
      ov[2] = (f16)(o[fo][2] * inv); ov[3] = (f16)(o[fo][3] * inv);
      *(f16x4*)dst = ov;
    }
  }
}

// ------------- output GEMM: 128x64 tile, BK=64, f32 out + bias -------------
__global__ __launch_bounds__(256) void ogemm_kernel(
    const f16* __restrict__ Aimg, const f16* __restrict__ Bimg,
    const float* __restrict__ bias, float* __restrict__ out) {
  __shared__ f16 As[8192];
  __shared__ f16 Bs[4096];
  int lin = blockIdx.x + (blockIdx.y << 4);
  int swz = ((lin & 7) << 6) + (lin >> 3);
  const int n0 = (swz & 15) * 64, m0 = (swz >> 4) * 128;
  const int tid = threadIdx.x, w = tid >> 6, l = tid & 63, q = l & 15, g = l >> 4;
  const int wr = w >> 1, wc = w & 1;
  int aoff[4][2], boff[2][2];
#pragma unroll
  for (int mi = 0; mi < 4; mi++) {
    int mr = wr * 64 + mi * 16 + q;
#pragma unroll
    for (int kb = 0; kb < 2; kb++)
      aoff[mi][kb] = (((mr >> 6) << 1) | kb) * 2048 + imgAB(mr & 63, g * 8);
  }
#pragma unroll
  for (int ni = 0; ni < 2; ni++) {
    int nr = wc * 32 + ni * 16 + q;
#pragma unroll
    for (int kb = 0; kb < 2; kb++)
      boff[ni][kb] = kb * 2048 + imgAB(nr & 63, g * 8);
  }
  f32x4 acc[4][2] = {};
  for (int t = 0; t < 16; t++) {
#pragma unroll
    for (int i = 0; i < 4; i++) {
      int c = w * 4 + i;
      int bi = c >> 2, part = c & 3;
      size_t gblk = (size_t)(((m0 >> 6) + (bi >> 1)) * 32 + t * 2 + (bi & 1));
      GLOBAL_LOAD_LDS16(Aimg + gblk * 2048 + part * 512 + l * 8, (char*)&As[c * 512]);
    }
#pragma unroll
    for (int i = 0; i < 2; i++) {
      int c = w * 2 + i;
      int bi = c >> 2, part = c & 3;
      size_t gblk = (size_t)((n0 >> 6) * 32 + t * 2 + (bi & 1));
      GLOBAL_LOAD_LDS16(Bimg + gblk * 2048 + part * 512 + l * 8, (char*)&Bs[c * 512]);
    }
    __syncthreads();
    f16x8 af[4][2], bf[2][2];
#pragma unroll
    for (int mi = 0; mi < 4; mi++) {
      af[mi][0] = *(const f16x8*)&As[aoff[mi][0]];
      af[mi][1] = *(const f16x8*)&As[aoff[mi][1]];
    }
#pragma unroll
    for (int ni = 0; ni < 2; ni++) {
      bf[ni][0] = *(const f16x8*)&Bs[boff[ni][0]];
      bf[ni][1] = *(const f16x8*)&Bs[boff[ni][1]];
    }
#pragma unroll
    for (int mi = 0; mi < 4; mi++)
#pragma unroll
      for (int ni = 0; ni < 2; ni++) {
        acc[mi][ni] = MFMA16(af[mi][0], bf[ni][0], acc[mi][ni]);
        acc[mi][ni] = MFMA16(af[mi][1], bf[ni][1], acc[mi][ni]);
      }
    __syncthreads();
  }
#pragma unroll
  for (int mi = 0; mi < 4; mi++)
#pragma unroll
    for (int ni = 0; ni < 2; ni++) {
      const int col = n0 + wc * 32 + ni * 16 + q;
      const float bvl = bias[col];
      const int row0 = m0 + wr * 64 + mi * 16 + g * 4;
#pragma unroll
      for (int r = 0; r < 4; r++)
        out[(size_t)(row0 + r) * DMODEL + col] = acc[mi][ni][r] + bvl;
    }
}

extern "C" void kernel_launch(void* const* d_in, const int* in_sizes, int n_in,
                              void* d_out, int out_size, void* d_ws, size_t ws_size,
                              hipStream_t stream) {
  const float* q  = (const float*)d_in[0];
  const float* k  = (const float*)d_in[1];
  const float* v  = (const float*)d_in[2];
  const float* wq = (const float*)d_in[3];
  const float* bq = (const float*)d_in[4];
  const float* wk = (const float*)d_in[5];
  const float* bk = (const float*)d_in[6];
  const float* wv = (const float*)d_in[7];
  const float* bv = (const float*)d_in[8];
  const float* wo = (const float*)d_in[9];
  const float* bo = (const float*)d_in[10];

  const size_t XSZ = (size_t)MTOK * DMODEL;  // 4M f16 = 8MB
  f16* ws = (f16*)d_ws;
  const bool fused = ws_size >= (56ull << 20);

  f16 *X0, *X1, *X2, *Qp, *Kp, *Vt, *Wimg, *scr;
  if (fused) {
    X0 = ws; X1 = ws + XSZ; X2 = ws + 2 * XSZ;
    Qp = ws + 3 * XSZ; Kp = ws + 4 * XSZ; Vt = ws + 5 * XSZ;
    Wimg = ws + 6 * XSZ;
    scr = X0;
  } else {
    X0 = X1 = X2 = ws;
    Qp = ws + XSZ; Kp = ws + 2 * XSZ; Vt = ws + 3 * XSZ;
    Wimg = ws + 4 * XSZ;
    scr = X0;
  }

  dim3 blk(256);
  dim3 gT(16, 16, 4);
  dim3 gC(2048);
  dim3 gA(2048);
  dim3 gO(16, 32);

  transw_kernel<<<gT, blk, 0, stream>>>(wq, wk, wv, wo, Wimg);

  if (fused) {
    cast_kernel<<<gC, blk, 0, stream>>>(q, X0);
    cast_kernel<<<gC, blk, 0, stream>>>(k, X1);
    cast_kernel<<<gC, blk, 0, stream>>>(v, X2);
    proj_kernel<<<dim3(8, 32, 3), blk, 0, stream>>>(X0, Wimg, bq, bk, bv, Qp, Kp, Vt, 0, XSZ);
  } else {
    cast_kernel<<<gC, blk, 0, stream>>>(q, X0);
    proj_kernel<<<dim3(8, 32, 1), blk, 0, stream>>>(X0, Wimg, bq, bk, bv, Qp, Kp, Vt, 0, 0);
    cast_kernel<<<gC, blk, 0, stream>>>(k, X0);
    proj_kernel<<<dim3(8, 32, 1), blk, 0, stream>>>(X0, Wimg, bq, bk, bv, Qp, Kp, Vt, 1, 0);
    cast_kernel<<<gC, blk, 0, stream>>>(v, X0);
    proj_kernel<<<dim3(8, 32, 1), blk, 0, stream>>>(X0, Wimg, bq, bk, bv, Qp, Kp, Vt, 2, 0);
  }

  attn_kernel<<<gA, dim3(64), 0, stream>>>(Qp, Kp, Vt, scr);
  ogemm_kernel<<<gO, blk, 0, stream>>>(scr, Wimg + (size_t)3 * DMODEL * DMODEL, bo, (float*)d_out);
}

// Round 5
// 244.039 us; speedup vs baseline: 1.2421x; 1.2421x over previous
//
#include <hip/hip_runtime.h>

typedef _Float16 f16;
typedef _Float16 f16x8 __attribute__((ext_vector_type(8)));
typedef _Float16 f16x4 __attribute__((ext_vector_type(4)));
typedef float    f32x4 __attribute__((ext_vector_type(4)));

static constexpr int BATCH = 2, SEQ = 2048, DMODEL = 1024, HEADS = 16, DHEAD = 64;
static constexpr int MTOK = BATCH * SEQ;  // 4096 tokens
static constexpr float LOG2E = 1.44269504088896f;

// async global->LDS, 16B per lane, LDS dest = wave-uniform base + lane*16
#define GLOBAL_LOAD_LDS16(gptr, lptr)                                              \
  __builtin_amdgcn_global_load_lds(                                                \
      (const __attribute__((address_space(1))) void*)(gptr),                       \
      (__attribute__((address_space(3))) void*)(lptr), 16, 0, 0)

#define MFMA16(a, b, c) __builtin_amdgcn_mfma_f32_16x16x32_f16((a), (b), (c), 0, 0, 0)

// counted vmcnt wait (memory clobber pins surrounding ds/global ops)
#define WAITV_(N) asm volatile("s_waitcnt vmcnt(" #N ")" ::: "memory")
#define WAITV(N) WAITV_(N)

__device__ __forceinline__ float fexp2(float x) {
  float r;
  asm volatile("v_exp_f32 %0, %1" : "=v"(r) : "v"(x));
  return r;
}

// ---- 64x32 f16 image block (4KB = 2048 f16), paired-row XOR swizzle ----
__device__ __forceinline__ int imgAB(int mr, int kr) {
  int pr = mr >> 1;
  int jj = ((mr & 1) << 2) | (kr >> 3);
  int j = jj ^ (pr & 7);
  return pr * 64 + j * 8 + (kr & 7);
}
// K image: 32 s-rows x 64 dh, full-row swizzle
__device__ __forceinline__ int imgK(int sr, int dh) {
  return sr * 64 + (((dh >> 3) ^ (sr & 7)) << 3) + (dh & 7);
}

// ---------------- cast fp32 -> f16 image layout ----------------
__global__ __launch_bounds__(256) void cast_kernel(const float* __restrict__ src,
                                                   f16* __restrict__ dst) {
  int c = blockIdx.x * 256 + threadIdx.x;  // chunk id
  int blk = c >> 8, cb = c & 255;
  int pr = cb >> 3, j = cb & 7;
  int jj = j ^ (pr & 7);
  int mr = (pr << 1) | (jj >> 2);
  int kr = (jj & 3) << 3;
  int m = (blk >> 5) * 64 + mr;
  int k = (blk & 31) * 32 + kr;
  const float* s = src + (size_t)m * DMODEL + k;
  f32x4 a = *(const f32x4*)s, b = *(const f32x4*)(s + 4);
  f16x8 o;
  o[0] = (f16)a[0]; o[1] = (f16)a[1]; o[2] = (f16)a[2]; o[3] = (f16)a[3];
  o[4] = (f16)b[0]; o[5] = (f16)b[1]; o[6] = (f16)b[2]; o[7] = (f16)b[3];
  *(f16x8*)(dst + (size_t)c * 8) = o;
}

// ------------- weight transpose+cast to image: B[n][k] = w[k][n] -------------
__global__ __launch_bounds__(256) void transw_kernel(
    const float* __restrict__ w0, const float* __restrict__ w1,
    const float* __restrict__ w2, const float* __restrict__ w3,
    f16* __restrict__ Wimg) {
  const int z = blockIdx.z;
  const float* w = z == 0 ? w0 : z == 1 ? w1 : z == 2 ? w2 : w3;
  f16* t = Wimg + (size_t)z * DMODEL * DMODEL;
  __shared__ f16 lt[64][72];
  const int k0 = blockIdx.x * 64, n0 = blockIdx.y * 64;
  const int r = threadIdx.x >> 2, c0 = (threadIdx.x & 3) * 16;
  const float* src = w + (size_t)(k0 + r) * DMODEL + n0 + c0;
#pragma unroll
  for (int jx = 0; jx < 16; jx += 4) {
    f32x4 x = *(const f32x4*)(src + jx);
    lt[c0 + jx + 0][r] = (f16)x[0];
    lt[c0 + jx + 1][r] = (f16)x[1];
    lt[c0 + jx + 2][r] = (f16)x[2];
    lt[c0 + jx + 3][r] = (f16)x[3];
  }
  __syncthreads();
  const int n = n0 + r;
#pragma unroll
  for (int cw = 0; cw < 2; cw++) {
    int k = k0 + c0 + cw * 8;
    int blk = ((n >> 6) << 5) | (k >> 5);
    int off = blk * 2048 + imgAB(n & 63, k & 31);
    f16x8 v;
#pragma unroll
    for (int e = 0; e < 8; e++) v[e] = lt[r][c0 + cw * 8 + e];
    *(f16x8*)(t + off) = v;
  }
}

// ------- fused QKV projection GEMM: 128x128 tile, BK=32, 4 waves, z-fused ------
// Double-buffered LDS + counted vmcnt + raw barriers (no full drain in loop).
// z=0: Qp linear f16 scaled by log2(e). z=1: Kp K-image. z=2: Vt V-image.
__global__ __launch_bounds__(256) void proj_kernel(
    const f16* __restrict__ Ximg, const f16* __restrict__ Wimg,
    const float* __restrict__ bq, const float* __restrict__ bk,
    const float* __restrict__ bv, f16* __restrict__ Qp, f16* __restrict__ Kp,
    f16* __restrict__ Vt, int zbase, size_t aStride) {
  __shared__ f16 As[2][4096];
  __shared__ f16 Bs[2][4096];
  const int z = zbase + blockIdx.z;
  const f16* A = Ximg + (size_t)blockIdx.z * aStride;
  const f16* Bw = Wimg + (size_t)z * DMODEL * DMODEL;
  int lin = blockIdx.x + (blockIdx.y << 3);
  int swz = ((lin & 7) << 5) + (lin >> 3);
  const int n0 = (swz & 7) * 128, m0 = (swz >> 3) * 128;
  const int tid = threadIdx.x, w = tid >> 6, l = tid & 63, q = l & 15, g = l >> 4;
  const int wr = w >> 1, wc = w & 1;
  const int KT = DMODEL >> 5;  // 32 k-tiles
  int aoff[4], boff[4];
#pragma unroll
  for (int mi = 0; mi < 4; mi++) {
    int mr = wr * 64 + mi * 16 + q;
    aoff[mi] = ((mr >> 6) << 11) + imgAB(mr & 63, g * 8);
  }
#pragma unroll
  for (int ni = 0; ni < 4; ni++) {
    int nr = wc * 64 + ni * 16 + q;
    boff[ni] = ((nr >> 6) << 11) + imgAB(nr & 63, g * 8);
  }
  f32x4 acc[4][4] = {};

#define PROJ_STAGE(bb, t)                                                          \
  {                                                                                \
    _Pragma("unroll")                                                              \
    for (int i = 0; i < 2; i++) {                                                  \
      int c = w * 2 + i;                                                           \
      size_t ga = (size_t)(((m0 >> 6) + (c >> 2)) * KT + (t)) * 2048 +             \
                  (c & 3) * 512 + l * 8;                                           \
      GLOBAL_LOAD_LDS16(A + ga, (char*)&As[bb][c * 512]);                          \
      size_t gb = (size_t)(((n0 >> 6) + (c >> 2)) * KT + (t)) * 2048 +             \
                  (c & 3) * 512 + l * 8;                                           \
      GLOBAL_LOAD_LDS16(Bw + gb, (char*)&Bs[bb][c * 512]);                         \
    }                                                                              \
  }

  PROJ_STAGE(0, 0);
  for (int t = 0; t < KT; t++) {
    const int bb = t & 1;
    if (t < KT - 1) {
      PROJ_STAGE(bb ^ 1, t + 1);
      WAITV(4);
    } else {
      WAITV(0);
    }
    __builtin_amdgcn_s_barrier();
    f16x8 af[4], bf[4];
#pragma unroll
    for (int mi = 0; mi < 4; mi++) af[mi] = *(const f16x8*)&As[bb][aoff[mi]];
#pragma unroll
    for (int ni = 0; ni < 4; ni++) bf[ni] = *(const f16x8*)&Bs[bb][boff[ni]];
#pragma unroll
    for (int mi = 0; mi < 4; mi++)
#pragma unroll
      for (int ni = 0; ni < 4; ni++)
        acc[mi][ni] = MFMA16(af[mi], bf[ni], acc[mi][ni]);
    __builtin_amdgcn_s_barrier();
  }
  const float* bias = z == 0 ? bq : (z == 1 ? bk : bv);
#pragma unroll
  for (int mi = 0; mi < 4; mi++)
#pragma unroll
    for (int ni = 0; ni < 4; ni++) {
      const int col = n0 + wc * 64 + ni * 16 + q;
      const float bvl = bias[col];
      const int row0 = m0 + wr * 64 + mi * 16 + g * 4;
      if (z == 0) {
#pragma unroll
        for (int r = 0; r < 4; r++)
          Qp[(size_t)(row0 + r) * DMODEL + col] = (f16)((acc[mi][ni][r] + bvl) * LOG2E);
      } else if (z == 1) {
        const int h = col >> 6, dh = col & 63;
#pragma unroll
        for (int r = 0; r < 4; r++) {
          const int row = row0 + r, s = row & (SEQ - 1);
          Kp[(size_t)(((row >> 11) * HEADS + h) * 64 + (s >> 5)) * 2048 + imgK(s & 31, dh)] =
              (f16)(acc[mi][ni][r] + bvl);
        }
      } else {
        const int h = col >> 6, dh = col & 63;
        const int s0 = row0 & (SEQ - 1);
        f16* dst = Vt + (size_t)(((row0 >> 11) * HEADS + h) * 64 + (s0 >> 5)) * 2048 +
                   imgAB(dh, s0 & 31);
        f16x4 ov;
        ov[0] = (f16)(acc[mi][ni][0] + bvl); ov[1] = (f16)(acc[mi][ni][1] + bvl);
        ov[2] = (f16)(acc[mi][ni][2] + bvl); ov[3] = (f16)(acc[mi][ni][3] + bvl);
        *(f16x4*)dst = ov;
      }
    }
}

// ---------------- flash attention (scores pre-scaled by log2e) ----------------
// grid 1024, 4 waves x 16 q-rows, KVBLK=64, dbuf LDS (40KB, 4 blocks/CU),
// counted vmcnt + raw barrier pair per iter (prefetch stays in flight).
// Swapped MFMAs keep softmax lane-local; defer-max skips rescale on most tiles.
// Output written in out-GEMM image layout with the reference's transpose-bug
// scramble: b'=h>>3, s'=((2h+b)&15)*128+s/16, d'=(s%16)*64+dh.
__global__ __launch_bounds__(256, 4) void attn_kernel(
    const f16* __restrict__ Qp, const f16* __restrict__ Kimg,
    const f16* __restrict__ Vimg, f16* __restrict__ Simg) {
  __shared__ f16 Klds[2][2][2048];
  __shared__ f16 Vlds[2][2][2048];
  __shared__ f16 Plds[4][2][512];
  const int tid = threadIdx.x, w = tid >> 6, l = tid & 63, q = l & 15, g = l >> 4;
  const int lin = blockIdx.x;
  const int swz = ((lin & 7) << 7) + (lin >> 3);  // XCD chunking: 4 heads/XCD
  const int qb = swz & 31, bh = swz >> 5;
  const int b = bh >> 4, h = bh & 15;
  const int q0 = qb * 64 + w * 16;

  const f16* qrow = Qp + (size_t)(b * SEQ + q0 + q) * DMODEL + h * 64;
  const f16x8 qf0 = *(const f16x8*)(qrow + g * 8);
  const f16x8 qf1 = *(const f16x8*)(qrow + 32 + g * 8);
  const f16* kt_base = Kimg + (size_t)(bh * 64) * 2048;
  const f16* vt_base = Vimg + (size_t)(bh * 64) * 2048;

  int koff[4][2];
#pragma unroll
  for (int fn = 0; fn < 4; fn++)
#pragma unroll
    for (int hf = 0; hf < 2; hf++)
      koff[fn][hf] = (fn >> 1) * 2048 + imgK((fn & 1) * 16 + q, hf * 32 + g * 8);
  int voff[4];
#pragma unroll
  for (int fo = 0; fo < 4; fo++) voff[fo] = imgAB(fo * 16 + q, g * 8);
  const int poff = imgAB(q, g * 8);
  int pwoff[2];
  {
    const int pr = q >> 1;
#pragma unroll
    for (int fn = 0; fn < 2; fn++) {
      int jj = ((q & 1) << 2) | (fn * 2 + (g >> 1));
      pwoff[fn] = pr * 64 + ((jj ^ (pr & 7)) << 3) + (g & 1) * 4;
    }
  }
  float m_st = -1.0e30f, l_pt = 0.f;
  f32x4 o_acc[4] = {};

  // wave w stages one 4KB image block: w0/w1 -> K sub 0/1, w2/w3 -> V sub 0/1
#define ATTN_STAGE(bb, t)                                                          \
  {                                                                                \
    const f16* sb_ = (w < 2) ? (kt_base + (size_t)(2 * (t) + w) * 2048)            \
                             : (vt_base + (size_t)(2 * (t) + (w - 2)) * 2048);     \
    f16* db_ = (w < 2) ? &Klds[bb][w][0] : &Vlds[bb][w - 2][0];                    \
    _Pragma("unroll")                                                              \
    for (int j_ = 0; j_ < 4; j_++)                                                 \
      GLOBAL_LOAD_LDS16(sb_ + j_ * 512 + l * 8, (char*)(db_ + j_ * 512));          \
  }

  ATTN_STAGE(0, 0);
  for (int t = 0; t < 32; t++) {
    const int bb = t & 1;
    if (t < 31) {
      ATTN_STAGE(bb ^ 1, t + 1);
      WAITV(4);
    } else {
      WAITV(0);
    }
    __builtin_amdgcn_s_barrier();
    // --- S^T tile (64k x 16q per wave), rows lane-local after swap ---
    const f16* Kb = &Klds[bb][0][0];
    f32x4 sacc[4];
#pragma unroll
    for (int fn = 0; fn < 4; fn++) {
      f32x4 zz = {};
      zz = MFMA16(*(const f16x8*)(Kb + koff[fn][0]), qf0, zz);
      zz = MFMA16(*(const f16x8*)(Kb + koff[fn][1]), qf1, zz);
      sacc[fn] = zz;
    }
    // --- online softmax over 16 lane-local scores + defer-max ---
    float lm = fmaxf(
        fmaxf(fmaxf(fmaxf(sacc[0][0], sacc[0][1]), fmaxf(sacc[0][2], sacc[0][3])),
              fmaxf(fmaxf(sacc[1][0], sacc[1][1]), fmaxf(sacc[1][2], sacc[1][3]))),
        fmaxf(fmaxf(fmaxf(sacc[2][0], sacc[2][1]), fmaxf(sacc[2][2], sacc[2][3])),
              fmaxf(fmaxf(sacc[3][0], sacc[3][1]), fmaxf(sacc[3][2], sacc[3][3]))));
    if (!__all(lm <= m_st + 8.f)) {
      float mx = fmaxf(lm, __shfl_xor(lm, 16, 64));
      mx = fmaxf(mx, __shfl_xor(mx, 32, 64));
      const float mnew = fmaxf(m_st, mx);
      const float sc = fexp2(m_st - mnew);
      m_st = mnew;
      l_pt *= sc;
#pragma unroll
      for (int fo = 0; fo < 4; fo++) {
        o_acc[fo][0] *= sc; o_acc[fo][1] *= sc;
        o_acc[fo][2] *= sc; o_acc[fo][3] *= sc;
      }
    }
    float ts = 0.f;
#pragma unroll
    for (int fn = 0; fn < 4; fn++) {
      f16x4 pk;
#pragma unroll
      for (int r = 0; r < 4; r++) {
        float e = fexp2(sacc[fn][r] - m_st);
        ts += e;
        pk[r] = (f16)e;
      }
      *(f16x4*)(&Plds[w][fn >> 1][0] + pwoff[fn & 1]) = pk;
    }
    l_pt += ts;
    const f16x8 p0 = *(const f16x8*)(&Plds[w][0][0] + poff);
    const f16x8 p1 = *(const f16x8*)(&Plds[w][1][0] + poff);
    // --- O^T += V^T . P^T over the 64-k tile ---
    const f16* Vb = &Vlds[bb][0][0];
#pragma unroll
    for (int fo = 0; fo < 4; fo++) {
      o_acc[fo] = MFMA16(*(const f16x8*)(Vb + voff[fo]), p0, o_acc[fo]);
      o_acc[fo] = MFMA16(*(const f16x8*)(Vb + 2048 + voff[fo]), p1, o_acc[fo]);
    }
    __builtin_amdgcn_s_barrier();
  }
  // --- finalize + scrambled store ---
  float lsum = l_pt + __shfl_xor(l_pt, 16, 64);
  lsum += __shfl_xor(lsum, 32, 64);
  const float inv = 1.f / lsum;
  const int s = q0 + q;
  const int m16 = (2 * h + b) & 15, bp = h >> 3;
  const int tp = bp * SEQ + m16 * 128 + (s >> 4);
#pragma unroll
  for (int fo = 0; fo < 4; fo++) {
    const int d0 = (s & 15) * 64 + fo * 16 + g * 4;
    f16* dst = Simg + (size_t)(((tp >> 6) << 5) | (d0 >> 5)) * 2048 + imgAB(tp & 63, d0 & 31);
    f16x4 ov;
    ov[0] = (f16)(o_acc[fo][0] * inv); ov[1] = (f16)(o_acc[fo][1] * inv);
    ov[2] = (f16)(o_acc[fo][2] * inv); ov[3] = (f16)(o_acc[fo][3] * inv);
    *(f16x4*)dst = ov;
  }
}

// ------------- output GEMM: 128x64 tile, BK=32, dbuf + counted vmcnt -------------
__global__ __launch_bounds__(256) void ogemm_kernel(
    const f16* __restrict__ Aimg, const f16* __restrict__ Bimg,
    const float* __restrict__ bias, float* __restrict__ out) {
  __shared__ f16 As[2][4096];
  __shared__ f16 Bs[2][2048];
  int lin = blockIdx.x + (blockIdx.y << 4);
  int swz = ((lin & 7) << 6) + (lin >> 3);
  const int n0 = (swz & 15) * 64, m0 = (swz >> 4) * 128;
  const int tid = threadIdx.x, w = tid >> 6, l = tid & 63, q = l & 15, g = l >> 4;
  const int wr = w >> 1, wc = w & 1;
  int aoff[4], boff[2];
#pragma unroll
  for (int mi = 0; mi < 4; mi++) {
    int mr = wr * 64 + mi * 16 + q;
    aoff[mi] = ((mr >> 6) << 11) + imgAB(mr & 63, g * 8);
  }
#pragma unroll
  for (int ni = 0; ni < 2; ni++) boff[ni] = imgAB(wc * 32 + ni * 16 + q, g * 8);
  f32x4 acc[4][2] = {};

#define OG_STAGE(bb, t)                                                            \
  {                                                                                \
    _Pragma("unroll")                                                              \
    for (int i = 0; i < 2; i++) {                                                  \
      int c = w * 2 + i;                                                           \
      size_t ga = (size_t)(((m0 >> 6) + (c >> 2)) * 32 + (t)) * 2048 +             \
                  (c & 3) * 512 + l * 8;                                           \
      GLOBAL_LOAD_LDS16(Aimg + ga, (char*)&As[bb][c * 512]);                       \
    }                                                                              \
    size_t gb = (size_t)((n0 >> 6) * 32 + (t)) * 2048 + w * 512 + l * 8;           \
    GLOBAL_LOAD_LDS16(Bimg + gb, (char*)&Bs[bb][w * 512]);                         \
  }

  OG_STAGE(0, 0);
  for (int t = 0; t < 32; t++) {
    const int bb = t & 1;
    if (t < 31) {
      OG_STAGE(bb ^ 1, t + 1);
      WAITV(3);
    } else {
      WAITV(0);
    }
    __builtin_amdgcn_s_barrier();
    f16x8 af[4], bf[2];
#pragma unroll
    for (int mi = 0; mi < 4; mi++) af[mi] = *(const f16x8*)&As[bb][aoff[mi]];
#pragma unroll
    for (int ni = 0; ni < 2; ni++) bf[ni] = *(const f16x8*)&Bs[bb][boff[ni]];
#pragma unroll
    for (int mi = 0; mi < 4; mi++)
#pragma unroll
      for (int ni = 0; ni < 2; ni++)
        acc[mi][ni] = MFMA16(af[mi], bf[ni], acc[mi][ni]);
    __builtin_amdgcn_s_barrier();
  }
#pragma unroll
  for (int mi = 0; mi < 4; mi++)
#pragma unroll
    for (int ni = 0; ni < 2; ni++) {
      const int col = n0 + wc * 32 + ni * 16 + q;
      const float bvl = bias[col];
      const int row0 = m0 + wr * 64 + mi * 16 + g * 4;
#pragma unroll
      for (int r = 0; r < 4; r++)
        out[(size_t)(row0 + r) * DMODEL + col] = acc[mi][ni][r] + bvl;
    }
}

extern "C" void kernel_launch(void* const* d_in, const int* in_sizes, int n_in,
                              void* d_out, int out_size, void* d_ws, size_t ws_size,
                              hipStream_t stream) {
  const float* q  = (const float*)d_in[0];
  const float* k  = (const float*)d_in[1];
  const float* v  = (const float*)d_in[2];
  const float* wq = (const float*)d_in[3];
  const float* bq = (const float*)d_in[4];
  const float* wk = (const float*)d_in[5];
  const float* bk = (const float*)d_in[6];
  const float* wv = (const float*)d_in[7];
  const float* bv = (const float*)d_in[8];
  const float* wo = (const float*)d_in[9];
  const float* bo = (const float*)d_in[10];

  const size_t XSZ = (size_t)MTOK * DMODEL;  // 4M f16 = 8MB
  f16* ws = (f16*)d_ws;
  const bool fused = ws_size >= (56ull << 20);

  f16 *X0, *X1, *X2, *Qp, *Kp, *Vt, *Wimg, *scr;
  if (fused) {
    X0 = ws; X1 = ws + XSZ; X2 = ws + 2 * XSZ;
    Qp = ws + 3 * XSZ; Kp = ws + 4 * XSZ; Vt = ws + 5 * XSZ;
    Wimg = ws + 6 * XSZ;
    scr = X0;
  } else {
    X0 = X1 = X2 = ws;
    Qp = ws + XSZ; Kp = ws + 2 * XSZ; Vt = ws + 3 * XSZ;
    Wimg = ws + 4 * XSZ;
    scr = X0;
  }

  dim3 blk(256);
  dim3 gT(16, 16, 4);
  dim3 gC(2048);
  dim3 gA(1024);
  dim3 gO(16, 32);

  transw_kernel<<<gT, blk, 0, stream>>>(wq, wk, wv, wo, Wimg);

  if (fused) {
    cast_kernel<<<gC, blk, 0, stream>>>(q, X0);
    cast_kernel<<<gC, blk, 0, stream>>>(k, X1);
    cast_kernel<<<gC, blk, 0, stream>>>(v, X2);
    proj_kernel<<<dim3(8, 32, 3), blk, 0, stream>>>(X0, Wimg, bq, bk, bv, Qp, Kp, Vt, 0, XSZ);
  } else {
    cast_kernel<<<gC, blk, 0, stream>>>(q, X0);
    proj_kernel<<<dim3(8, 32, 1), blk, 0, stream>>>(X0, Wimg, bq, bk, bv, Qp, Kp, Vt, 0, 0);
    cast_kernel<<<gC, blk, 0, stream>>>(k, X0);
    proj_kernel<<<dim3(8, 32, 1), blk, 0, stream>>>(X0, Wimg, bq, bk, bv, Qp, Kp, Vt, 1, 0);
    cast_kernel<<<gC, blk, 0, stream>>>(v, X0);
    proj_kernel<<<dim3(8, 32, 1), blk, 0, stream>>>(X0, Wimg, bq, bk, bv, Qp, Kp, Vt, 2, 0);
  }

  attn_kernel<<<gA, blk, 0, stream>>>(Qp, Kp, Vt, scr);
  ogemm_kernel<<<gO, blk, 0, stream>>>(scr, Wimg + (size_t)3 * DMODEL * DMODEL, bo, (float*)d_out);
}

// Round 7
// 235.919 us; speedup vs baseline: 1.2849x; 1.0344x over previous
//
#include <hip/hip_runtime.h>

typedef _Float16 f16;
typedef _Float16 f16x8 __attribute__((ext_vector_type(8)));
typedef _Float16 f16x4 __attribute__((ext_vector_type(4)));
typedef __fp16   h16x2 __attribute__((ext_vector_type(2)));
typedef float    f32x4 __attribute__((ext_vector_type(4)));

static constexpr int BATCH = 2, SEQ = 2048, DMODEL = 1024, HEADS = 16, DHEAD = 64;
static constexpr int MTOK = BATCH * SEQ;  // 4096 tokens
static constexpr float LOG2E = 1.44269504088896f;

// async global->LDS, 16B per lane, LDS dest = wave-uniform base + lane*16
#define GLOBAL_LOAD_LDS16(gptr, lptr)                                              \
  __builtin_amdgcn_global_load_lds(                                                \
      (const __attribute__((address_space(1))) void*)(gptr),                       \
      (__attribute__((address_space(3))) void*)(lptr), 16, 0, 0)

#define MFMA16(a, b, c) __builtin_amdgcn_mfma_f32_16x16x32_f16((a), (b), (c), 0, 0, 0)

// counted vmcnt wait (memory clobber pins surrounding ds/global ops)
#define WAITV_(N) asm volatile("s_waitcnt vmcnt(" #N ")" ::: "memory")
#define WAITV(N) WAITV_(N)

__device__ __forceinline__ float fexp2(float x) {
  float r;
  asm volatile("v_exp_f32 %0, %1" : "=v"(r) : "v"(x));
  return r;
}
__device__ __forceinline__ float m3(float a, float b, float c) {
  return fmaxf(fmaxf(a, b), c);  // clang fuses to v_max3_f32
}

// ---- 64x32 f16 image block (4KB = 2048 f16), paired-row XOR swizzle ----
__device__ __forceinline__ int imgAB(int mr, int kr) {
  int pr = mr >> 1;
  int jj = ((mr & 1) << 2) | (kr >> 3);
  int j = jj ^ (pr & 7);
  return pr * 64 + j * 8 + (kr & 7);
}
// K image: 32 s-rows x 64 dh, full-row swizzle
__device__ __forceinline__ int imgK(int sr, int dh) {
  return sr * 64 + (((dh >> 3) ^ (sr & 7)) << 3) + (dh & 7);
}

// ---------------- cast fp32 -> f16 image layout (z selects q/k/v) ----------------
__global__ __launch_bounds__(256) void cast3_kernel(
    const float* __restrict__ qs, const float* __restrict__ ks,
    const float* __restrict__ vs, f16* __restrict__ X0, f16* __restrict__ X1,
    f16* __restrict__ X2) {
  const int z = blockIdx.z;
  const float* src = z == 0 ? qs : z == 1 ? ks : vs;
  f16* dst = z == 0 ? X0 : z == 1 ? X1 : X2;
  int c = blockIdx.x * 256 + threadIdx.x;  // chunk id
  int blk = c >> 8, cb = c & 255;
  int pr = cb >> 3, j = cb & 7;
  int jj = j ^ (pr & 7);
  int mr = (pr << 1) | (jj >> 2);
  int kr = (jj & 3) << 3;
  int m = (blk >> 5) * 64 + mr;
  int k = (blk & 31) * 32 + kr;
  const float* s = src + (size_t)m * DMODEL + k;
  f32x4 a = *(const f32x4*)s, b = *(const f32x4*)(s + 4);
  f16x8 o;
  o[0] = (f16)a[0]; o[1] = (f16)a[1]; o[2] = (f16)a[2]; o[3] = (f16)a[3];
  o[4] = (f16)b[0]; o[5] = (f16)b[1]; o[6] = (f16)b[2]; o[7] = (f16)b[3];
  *(f16x8*)(dst + (size_t)c * 8) = o;
}

// ------------- weight transpose+cast to image: B[n][k] = w[k][n] -------------
__global__ __launch_bounds__(256) void transw_kernel(
    const float* __restrict__ w0, const float* __restrict__ w1,
    const float* __restrict__ w2, const float* __restrict__ w3,
    f16* __restrict__ Wimg) {
  const int z = blockIdx.z;
  const float* w = z == 0 ? w0 : z == 1 ? w1 : z == 2 ? w2 : w3;
  f16* t = Wimg + (size_t)z * DMODEL * DMODEL;
  __shared__ f16 lt[64][72];
  const int k0 = blockIdx.x * 64, n0 = blockIdx.y * 64;
  const int r = threadIdx.x >> 2, c0 = (threadIdx.x & 3) * 16;
  const float* src = w + (size_t)(k0 + r) * DMODEL + n0 + c0;
#pragma unroll
  for (int jx = 0; jx < 16; jx += 4) {
    f32x4 x = *(const f32x4*)(src + jx);
    lt[c0 + jx + 0][r] = (f16)x[0];
    lt[c0 + jx + 1][r] = (f16)x[1];
    lt[c0 + jx + 2][r] = (f16)x[2];
    lt[c0 + jx + 3][r] = (f16)x[3];
  }
  __syncthreads();
  const int n = n0 + r;
#pragma unroll
  for (int cw = 0; cw < 2; cw++) {
    int k = k0 + c0 + cw * 8;
    int blk = ((n >> 6) << 5) | (k >> 5);
    int off = blk * 2048 + imgAB(n & 63, k & 31);
    f16x8 v;
#pragma unroll
    for (int e = 0; e < 8; e++) v[e] = lt[r][c0 + cw * 8 + e];
    *(f16x8*)(t + off) = v;
  }
}

// ------- fused QKV projection GEMM: 128x128 tile, BK=32, 4 waves, z-fused ------
// Double-buffered LDS + counted vmcnt + raw barriers (no full drain in loop).
// z=0: Qp linear f16 scaled by log2(e). z=1: Kp K-image. z=2: Vt V-image.
__global__ __launch_bounds__(256) void proj_kernel(
    const f16* __restrict__ Ximg, const f16* __restrict__ Wimg,
    const float* __restrict__ bq, const float* __restrict__ bk,
    const float* __restrict__ bv, f16* __restrict__ Qp, f16* __restrict__ Kp,
    f16* __restrict__ Vt, int zbase, size_t aStride) {
  __shared__ f16 As[2][4096];
  __shared__ f16 Bs[2][4096];
  const int z = zbase + blockIdx.z;
  const f16* A = Ximg + (size_t)blockIdx.z * aStride;
  const f16* Bw = Wimg + (size_t)z * DMODEL * DMODEL;
  int lin = blockIdx.x + (blockIdx.y << 3);
  int swz = ((lin & 7) << 5) + (lin >> 3);
  const int n0 = (swz & 7) * 128, m0 = (swz >> 3) * 128;
  const int tid = threadIdx.x, w = tid >> 6, l = tid & 63, q = l & 15, g = l >> 4;
  const int wr = w >> 1, wc = w & 1;
  const int KT = DMODEL >> 5;  // 32 k-tiles
  int aoff[4], boff[4];
#pragma unroll
  for (int mi = 0; mi < 4; mi++) {
    int mr = wr * 64 + mi * 16 + q;
    aoff[mi] = ((mr >> 6) << 11) + imgAB(mr & 63, g * 8);
  }
#pragma unroll
  for (int ni = 0; ni < 4; ni++) {
    int nr = wc * 64 + ni * 16 + q;
    boff[ni] = ((nr >> 6) << 11) + imgAB(nr & 63, g * 8);
  }
  f32x4 acc[4][4] = {};

#define PROJ_STAGE(bb, t)                                                          \
  {                                                                                \
    _Pragma("unroll")                                                              \
    for (int i = 0; i < 2; i++) {                                                  \
      int c = w * 2 + i;                                                           \
      size_t ga = (size_t)(((m0 >> 6) + (c >> 2)) * KT + (t)) * 2048 +             \
                  (c & 3) * 512 + l * 8;                                           \
      GLOBAL_LOAD_LDS16(A + ga, (char*)&As[bb][c * 512]);                          \
      size_t gb = (size_t)(((n0 >> 6) + (c >> 2)) * KT + (t)) * 2048 +             \
                  (c & 3) * 512 + l * 8;                                           \
      GLOBAL_LOAD_LDS16(Bw + gb, (char*)&Bs[bb][c * 512]);                         \
    }                                                                              \
  }

  PROJ_STAGE(0, 0);
  for (int t = 0; t < KT; t++) {
    const int bb = t & 1;
    if (t < KT - 1) {
      PROJ_STAGE(bb ^ 1, t + 1);
      WAITV(4);
    } else {
      WAITV(0);
    }
    __builtin_amdgcn_s_barrier();
    f16x8 af[4], bf[4];
#pragma unroll
    for (int mi = 0; mi < 4; mi++) af[mi] = *(const f16x8*)&As[bb][aoff[mi]];
#pragma unroll
    for (int ni = 0; ni < 4; ni++) bf[ni] = *(const f16x8*)&Bs[bb][boff[ni]];
#pragma unroll
    for (int mi = 0; mi < 4; mi++)
#pragma unroll
      for (int ni = 0; ni < 4; ni++)
        acc[mi][ni] = MFMA16(af[mi], bf[ni], acc[mi][ni]);
    __builtin_amdgcn_s_barrier();
  }
  const float* bias = z == 0 ? bq : (z == 1 ? bk : bv);
#pragma unroll
  for (int mi = 0; mi < 4; mi++)
#pragma unroll
    for (int ni = 0; ni < 4; ni++) {
      const int col = n0 + wc * 64 + ni * 16 + q;
      const float bvl = bias[col];
      const int row0 = m0 + wr * 64 + mi * 16 + g * 4;
      if (z == 0) {
#pragma unroll
        for (int r = 0; r < 4; r++)
          Qp[(size_t)(row0 + r) * DMODEL + col] = (f16)((acc[mi][ni][r] + bvl) * LOG2E);
      } else if (z == 1) {
        const int h = col >> 6, dh = col & 63;
#pragma unroll
        for (int r = 0; r < 4; r++) {
          const int row = row0 + r, s = row & (SEQ - 1);
          Kp[(size_t)(((row >> 11) * HEADS + h) * 64 + (s >> 5)) * 2048 + imgK(s & 31, dh)] =
              (f16)(acc[mi][ni][r] + bvl);
        }
      } else {
        const int h = col >> 6, dh = col & 63;
        const int s0 = row0 & (SEQ - 1);
        f16* dst = Vt + (size_t)(((row0 >> 11) * HEADS + h) * 64 + (s0 >> 5)) * 2048 +
                   imgAB(dh, s0 & 31);
        f16x4 ov;
        ov[0] = (f16)(acc[mi][ni][0] + bvl); ov[1] = (f16)(acc[mi][ni][1] + bvl);
        ov[2] = (f16)(acc[mi][ni][2] + bvl); ov[3] = (f16)(acc[mi][ni][3] + bvl);
        *(f16x4*)dst = ov;
      }
    }
}

// ---------------- flash attention (scores pre-scaled by log2e) ----------------
// 2 waves x 32 q-rows (2 independent Q-fragments each), KVBLK=64, dbuf LDS
// (40KB = exactly 4 blocks/CU), counted vmcnt + raw barriers, setprio on MFMA.
// Fragment B's MFMA overlaps fragment A's softmax VALU; K/V ds_reads shared.
// Output written in out-GEMM image layout with the reference's transpose-bug
// scramble: b'=h>>3, s'=((2h+b)&15)*128+s/16, d'=(s%16)*64+dh.
__global__ __launch_bounds__(128, 2) void attn_kernel(
    const f16* __restrict__ Qp, const f16* __restrict__ Kimg,
    const f16* __restrict__ Vimg, f16* __restrict__ Simg) {
  __shared__ f16 Klds[2][2][2048];      // 16KB
  __shared__ f16 Vlds[2][2][2048];      // 16KB
  __shared__ f16 Plds[2][2][2][512];    // [wave][frag][half]  8KB
  const int tid = threadIdx.x, w = tid >> 6, l = tid & 63, q = l & 15, g = l >> 4;
  const int lin = blockIdx.x;
  const int swz = ((lin & 7) << 7) + (lin >> 3);  // XCD chunking: 4 heads/XCD
  const int qb = swz & 31, bh = swz >> 5;
  const int b = bh >> 4, h = bh & 15;
  const int q0 = qb * 64 + w * 32;

  const f16* qrowA = Qp + (size_t)(b * SEQ + q0 + q) * DMODEL + h * 64;
  const f16x8 qA0 = *(const f16x8*)(qrowA + g * 8);
  const f16x8 qA1 = *(const f16x8*)(qrowA + 32 + g * 8);
  const f16* qrowB = qrowA + (size_t)16 * DMODEL;
  const f16x8 qB0 = *(const f16x8*)(qrowB + g * 8);
  const f16x8 qB1 = *(const f16x8*)(qrowB + 32 + g * 8);

  const f16* kt_base = Kimg + (size_t)(bh * 64) * 2048;
  const f16* vt_base = Vimg + (size_t)(bh * 64) * 2048;

  int koff[4][2];
#pragma unroll
  for (int fn = 0; fn < 4; fn++)
#pragma unroll
    for (int hf = 0; hf < 2; hf++)
      koff[fn][hf] = (fn >> 1) * 2048 + imgK((fn & 1) * 16 + q, hf * 32 + g * 8);
  int voff[4];
#pragma unroll
  for (int fo = 0; fo < 4; fo++) voff[fo] = imgAB(fo * 16 + q, g * 8);
  const int poff = imgAB(q, g * 8);
  int pwoff[2];
  {
    const int pr = q >> 1;
#pragma unroll
    for (int fn = 0; fn < 2; fn++) {
      int jj = ((q & 1) << 2) | (fn * 2 + (g >> 1));
      pwoff[fn] = pr * 64 + ((jj ^ (pr & 7)) << 3) + (g & 1) * 4;
    }
  }
  f16* PwA = &Plds[w][0][0][0];
  f16* PwB = &Plds[w][1][0][0];
  float mA = -1.0e30f, mB = -1.0e30f, lA = 0.f, lB = 0.f;
  f32x4 oA[4] = {}, oB[4] = {};

  // wave 0 stages the 8KB K tile, wave 1 the 8KB V tile (8 x 1KB issues each)
#define ATTN_STAGE(bb, t)                                                          \
  {                                                                                \
    const f16* sb_ = (w == 0) ? (kt_base + (size_t)(2 * (t)) * 2048)               \
                              : (vt_base + (size_t)(2 * (t)) * 2048);              \
    f16* db_ = (w == 0) ? &Klds[bb][0][0] : &Vlds[bb][0][0];                       \
    _Pragma("unroll")                                                              \
    for (int j_ = 0; j_ < 8; j_++)                                                 \
      GLOBAL_LOAD_LDS16(sb_ + j_ * 512 + l * 8, (char*)(db_ + j_ * 512));          \
  }

#define SOFTMAX_FRAG(s, m_st, l_pt, o, PbF)                                        \
  {                                                                                \
    float lm = fmaxf(m3(m3(s[0][0], s[0][1], s[0][2]),                             \
                        m3(s[0][3], s[1][0], s[1][1]),                             \
                        m3(s[1][2], s[1][3], s[2][0])),                            \
                     m3(m3(s[2][1], s[2][2], s[2][3]),                             \
                        m3(s[3][0], s[3][1], s[3][2]), s[3][3]));                  \
    if (!__all(lm <= m_st + 8.f)) {                                                \
      float mx = fmaxf(lm, __shfl_xor(lm, 16, 64));                                \
      mx = fmaxf(mx, __shfl_xor(mx, 32, 64));                                      \
      const float mnew = fmaxf(m_st, mx);                                          \
      const float sc = fexp2(m_st - mnew);                                         \
      m_st = mnew;                                                                 \
      l_pt *= sc;                                                                  \
      _Pragma("unroll")                                                            \
      for (int fo_ = 0; fo_ < 4; fo_++) {                                          \
        o[fo_][0] *= sc; o[fo_][1] *= sc; o[fo_][2] *= sc; o[fo_][3] *= sc;        \
      }                                                                            \
    }                                                                              \
    float ts = 0.f;                                                                \
    _Pragma("unroll")                                                              \
    for (int fn_ = 0; fn_ < 4; fn_++) {                                            \
      float e0 = fexp2(s[fn_][0] - m_st);                                          \
      float e1 = fexp2(s[fn_][1] - m_st);                                          \
      float e2 = fexp2(s[fn_][2] - m_st);                                          \
      float e3 = fexp2(s[fn_][3] - m_st);                                          \
      ts += (e0 + e1) + (e2 + e3);                                                 \
      union { f16x4 v4; h16x2 h2[2]; } pu_;                                        \
      pu_.h2[0] = __builtin_amdgcn_cvt_pkrtz(e0, e1);                              \
      pu_.h2[1] = __builtin_amdgcn_cvt_pkrtz(e2, e3);                              \
      *(f16x4*)((PbF) + (fn_ >> 1) * 512 + pwoff[fn_ & 1]) = pu_.v4;               \
    }                                                                              \
    l_pt += ts;                                                                    \
  }

  ATTN_STAGE(0, 0);
  for (int t = 0; t < 32; t++) {
    const int bb = t & 1;
    if (t < 31) {
      ATTN_STAGE(bb ^ 1, t + 1);
      WAITV(8);
    } else {
      WAITV(0);
    }
    __builtin_amdgcn_s_barrier();
    const f16* Kb = &Klds[bb][0][0];
    f16x8 kf[4][2];
#pragma unroll
    for (int fn = 0; fn < 4; fn++) {
      kf[fn][0] = *(const f16x8*)(Kb + koff[fn][0]);
      kf[fn][1] = *(const f16x8*)(Kb + koff[fn][1]);
    }
    f32x4 sA[4], sB[4];
    __builtin_amdgcn_s_setprio(1);
#pragma unroll
    for (int fn = 0; fn < 4; fn++) {
      f32x4 z0 = {};
      z0 = MFMA16(kf[fn][0], qA0, z0);
      z0 = MFMA16(kf[fn][1], qA1, z0);
      sA[fn] = z0;
      f32x4 z1 = {};
      z1 = MFMA16(kf[fn][0], qB0, z1);
      z1 = MFMA16(kf[fn][1], qB1, z1);
      sB[fn] = z1;
    }
    __builtin_amdgcn_s_setprio(0);
    SOFTMAX_FRAG(sA, mA, lA, oA, PwA);
    SOFTMAX_FRAG(sB, mB, lB, oB, PwB);
    const f16x8 pA0 = *(const f16x8*)(PwA + poff);
    const f16x8 pA1 = *(const f16x8*)(PwA + 512 + poff);
    const f16x8 pB0 = *(const f16x8*)(PwB + poff);
    const f16x8 pB1 = *(const f16x8*)(PwB + 512 + poff);
    const f16* Vb = &Vlds[bb][0][0];
    f16x8 vf[4][2];
#pragma unroll
    for (int fo = 0; fo < 4; fo++) {
      vf[fo][0] = *(const f16x8*)(Vb + voff[fo]);
      vf[fo][1] = *(const f16x8*)(Vb + 2048 + voff[fo]);
    }
    __builtin_amdgcn_s_setprio(1);
#pragma unroll
    for (int fo = 0; fo < 4; fo++) {
      oA[fo] = MFMA16(vf[fo][0], pA0, oA[fo]);
      oA[fo] = MFMA16(vf[fo][1], pA1, oA[fo]);
      oB[fo] = MFMA16(vf[fo][0], pB0, oB[fo]);
      oB[fo] = MFMA16(vf[fo][1], pB1, oB[fo]);
    }
    __builtin_amdgcn_s_setprio(0);
    __builtin_amdgcn_s_barrier();
  }
  // --- finalize + scrambled store (both fragments) ---
  float lsA = lA + __shfl_xor(lA, 16, 64);
  lsA += __shfl_xor(lsA, 32, 64);
  float lsB = lB + __shfl_xor(lB, 16, 64);
  lsB += __shfl_xor(lsB, 32, 64);
  const float invA = 1.f / lsA, invB = 1.f / lsB;
  const int m16 = (2 * h + b) & 15, bp = h >> 3;
#pragma unroll
  for (int half = 0; half < 2; half++) {
    const int s = q0 + half * 16 + q;
    const int tp = bp * SEQ + m16 * 128 + (s >> 4);
    const float inv = half ? invB : invA;
    const f32x4* o = half ? oB : oA;
#pragma unroll
    for (int fo = 0; fo < 4; fo++) {
      const int d0 = (s & 15) * 64 + fo * 16 + g * 4;
      f16* dst = Simg + (size_t)(((tp >> 6) << 5) | (d0 >> 5)) * 2048 + imgAB(tp & 63, d0 & 31);
      f16x4 ov;
      ov[0] = (f16)(o[fo][0] * inv); ov[1] = (f16)(o[fo][1] * inv);
      ov[2] = (f16)(o[fo][2] * inv); ov[3] = (f16)(o[fo][3] * inv);
      *(f16x4*)dst = ov;
    }
  }
}

// ------------- output GEMM: 128x64 tile, BK=32, dbuf + counted vmcnt -------------
__global__ __launch_bounds__(256) void ogemm_kernel(
    const f16* __restrict__ Aimg, const f16* __restrict__ Bimg,
    const float* __restrict__ bias, float* __restrict__ out) {
  __shared__ f16 As[2][4096];
  __shared__ f16 Bs[2][2048];
  int lin = blockIdx.x + (blockIdx.y << 4);
  int swz = ((lin & 7) << 6) + (lin >> 3);
  const int n0 = (swz & 15) * 64, m0 = (swz >> 4) * 128;
  const int tid = threadIdx.x, w = tid >> 6, l = tid & 63, q = l & 15, g = l >> 4;
  const int wr = w >> 1, wc = w & 1;
  int aoff[4], boff[2];
#pragma unroll
  for (int mi = 0; mi < 4; mi++) {
    int mr = wr * 64 + mi * 16 + q;
    aoff[mi] = ((mr >> 6) << 11) + imgAB(mr & 63, g * 8);
  }
#pragma unroll
  for (int ni = 0; ni < 2; ni++) boff[ni] = imgAB(wc * 32 + ni * 16 + q, g * 8);
  f32x4 acc[4][2] = {};

#define OG_STAGE(bb, t)                                                            \
  {                                                                                \
    _Pragma("unroll")                                                              \
    for (int i = 0; i < 2; i++) {                                                  \
      int c = w * 2 + i;                                                           \
      size_t ga = (size_t)(((m0 >> 6) + (c >> 2)) * 32 + (t)) * 2048 +             \
                  (c & 3) * 512 + l * 8;                                           \
      GLOBAL_LOAD_LDS16(Aimg + ga, (char*)&As[bb][c * 512]);                       \
    }                                                                              \
    size_t gb = (size_t)((n0 >> 6) * 32 + (t)) * 2048 + w * 512 + l * 8;           \
    GLOBAL_LOAD_LDS16(Bimg + gb, (char*)&Bs[bb][w * 512]);                         \
  }

  OG_STAGE(0, 0);
  for (int t = 0; t < 32; t++) {
    const int bb = t & 1;
    if (t < 31) {
      OG_STAGE(bb ^ 1, t + 1);
      WAITV(3);
    } else {
      WAITV(0);
    }
    __builtin_amdgcn_s_barrier();
    f16x8 af[4], bf[2];
#pragma unroll
    for (int mi = 0; mi < 4; mi++) af[mi] = *(const f16x8*)&As[bb][aoff[mi]];
#pragma unroll
    for (int ni = 0; ni < 2; ni++) bf[ni] = *(const f16x8*)&Bs[bb][boff[ni]];
#pragma unroll
    for (int mi = 0; mi < 4; mi++)
#pragma unroll
      for (int ni = 0; ni < 2; ni++)
        acc[mi][ni] = MFMA16(af[mi], bf[ni], acc[mi][ni]);
    __builtin_amdgcn_s_barrier();
  }
#pragma unroll
  for (int mi = 0; mi < 4; mi++)
#pragma unroll
    for (int ni = 0; ni < 2; ni++) {
      const int col = n0 + wc * 32 + ni * 16 + q;
      const float bvl = bias[col];
      const int row0 = m0 + wr * 64 + mi * 16 + g * 4;
#pragma unroll
      for (int r = 0; r < 4; r++)
        out[(size_t)(row0 + r) * DMODEL + col] = acc[mi][ni][r] + bvl;
    }
}

extern "C" void kernel_launch(void* const* d_in, const int* in_sizes, int n_in,
                              void* d_out, int out_size, void* d_ws, size_t ws_size,
                              hipStream_t stream) {
  const float* q  = (const float*)d_in[0];
  const float* k  = (const float*)d_in[1];
  const float* v  = (const float*)d_in[2];
  const float* wq = (const float*)d_in[3];
  const float* bq = (const float*)d_in[4];
  const float* wk = (const float*)d_in[5];
  const float* bk = (const float*)d_in[6];
  const float* wv = (const float*)d_in[7];
  const float* bv = (const float*)d_in[8];
  const float* wo = (const float*)d_in[9];
  const float* bo = (const float*)d_in[10];

  const size_t XSZ = (size_t)MTOK * DMODEL;  // 4M f16 = 8MB
  f16* ws = (f16*)d_ws;
  const bool fused = ws_size >= (56ull << 20);

  f16 *X0, *X1, *X2, *Qp, *Kp, *Vt, *Wimg, *scr;
  if (fused) {
    X0 = ws; X1 = ws + XSZ; X2 = ws + 2 * XSZ;
    Qp = ws + 3 * XSZ; Kp = ws + 4 * XSZ; Vt = ws + 5 * XSZ;
    Wimg = ws + 6 * XSZ;
    scr = X0;
  } else {
    X0 = X1 = X2 = ws;
    Qp = ws + XSZ; Kp = ws + 2 * XSZ; Vt = ws + 3 * XSZ;
    Wimg = ws + 4 * XSZ;
    scr = X0;
  }

  dim3 blk(256), blk128(128);
  dim3 gT(16, 16, 4);
  dim3 gA(1024);
  dim3 gO(16, 32);

  transw_kernel<<<gT, blk, 0, stream>>>(wq, wk, wv, wo, Wimg);

  if (fused) {
    cast3_kernel<<<dim3(2048, 1, 3), blk, 0, stream>>>(q, k, v, X0, X1, X2);
    proj_kernel<<<dim3(8, 32, 3), blk, 0, stream>>>(X0, Wimg, bq, bk, bv, Qp, Kp, Vt, 0, XSZ);
  } else {
    cast3_kernel<<<dim3(2048, 1, 1), blk, 0, stream>>>(q, q, q, X0, X0, X0);
    proj_kernel<<<dim3(8, 32, 1), blk, 0, stream>>>(X0, Wimg, bq, bk, bv, Qp, Kp, Vt, 0, 0);
    cast3_kernel<<<dim3(2048, 1, 1), blk, 0, stream>>>(k, k, k, X0, X0, X0);
    proj_kernel<<<dim3(8, 32, 1), blk, 0, stream>>>(X0, Wimg, bq, bk, bv, Qp, Kp, Vt, 1, 0);
    cast3_kernel<<<dim3(2048, 1, 1), blk, 0, stream>>>(v, v, v, X0, X0, X0);
    proj_kernel<<<dim3(8, 32, 1), blk, 0, stream>>>(X0, Wimg, bq, bk, bv, Qp, Kp, Vt, 2, 0);
  }

  attn_kernel<<<gA, blk128, 0, stream>>>(Qp, Kp, Vt, scr);
  ogemm_kernel<<<gO, blk, 0, stream>>>(scr, Wimg + (size_t)3 * DMODEL * DMODEL, bo, (float*)d_out);
}